// Round 2
// baseline (840.095 us; speedup 1.0000x reference)
//
#include <hip/hip_runtime.h>

// Guided filter r=1, eps=0.01, (8,3,1024,1024) fp32.
// Register-streaming v2: vertical-sums-first, 4 cols/lane (float4), 2-register
// sliding vertical windows (p = prev2+prev1, r = prev1; v = p + new), single
// dependent DPP stage per box pass. Wave strip: 256 cols x 16 rows.
// Edge lanes maintain a 2-col halo pipeline. box()/Nrm == sum/count; count
// applied as exact 0.5 / (1/3) row x col factors.
//
// R1: __shfl -> DPP wave shifts (neutral; cross-lane latency was not the wall).
// R2: counters showed full serialization of memory and compute phases
//     (period 12.5k cy = 7.0k HBM-service + 5.6k VALU-issue; BW 2.4 TB/s =
//     6.3 * 7.0/12.5; VALUBusy 45% = 5.6/12.5). Convoy: all waves drain vmcnt
//     together. Fix: depth-2 row prefetch (consume waits on loads issued two
//     iterations ago) + sched_barrier(0) pin so the pressure-limited scheduler
//     cannot sink the loads to their use. launch_bounds(256,5) caps VGPR
//     growth; target <=85 VGPR to keep 6 blocks/CU resident.

#define H 1024
#define W 1024
#define STRIP 16      // output rows per wave
#define WAVES 4       // waves per block (stacked vertically)
#define WVC 256       // columns per wave (4 per lane)

// lane i receives lane i-1's value (== __shfl_up(v,1,64)); lane 0 -> 0
__device__ __forceinline__ float dpp_up1(float v) {
    return __int_as_float(__builtin_amdgcn_update_dpp(
        0, __float_as_int(v), 0x138 /*wave_shr:1*/, 0xf, 0xf, true));
}
// lane i receives lane i+1's value (== __shfl_down(v,1,64)); lane 63 -> 0
__device__ __forceinline__ float dpp_dn1(float v) {
    return __int_as_float(__builtin_amdgcn_update_dpp(
        0, __float_as_int(v), 0x130 /*wave_shl:1*/, 0xf, 0xf, true));
}

__global__ __launch_bounds__(256, 5) void gf_kernel(const float* __restrict__ xg,
                                                    const float* __restrict__ yg,
                                                    float* __restrict__ og)
{
    const int lane = threadIdx.x & 63;
    const int wv = threadIdx.x >> 6;
    const int c0 = blockIdx.x * WVC;
    const int R0 = (blockIdx.y * WAVES + wv) * STRIP;
    const size_t base = (size_t)blockIdx.z * (size_t)(H * W);
    const float* __restrict__ xp = xg + base;
    const float* __restrict__ yp = yg + base;
    float* __restrict__ op = og + base;

    const int colA = c0 + 4 * lane;          // first of this lane's 4 columns
    const bool isL = (lane == 0);
    const bool isR = (lane == 63);
    // lane0 halo cols: c0-2 (h0), c0-1 (h1).  lane63: c0+256 (h0), c0+257 (h1).
    const bool haloIn = isL ? (c0 > 0) : (isR ? (c0 + WVC < W) : false);
    const int hoff = (isL ? (c0 - 2) : (c0 + WVC)) - colA;

    const float third = 1.0f / 3.0f;
    float invc[4];
    invc[0] = (colA == 0) ? 0.5f : third;        // col%4==0 -> only col 0 possible edge
    invc[1] = third;
    invc[2] = third;
    invc[3] = (colA + 3 == W - 1) ? 0.5f : third;
    const float invcH = haloIn ? third : 0.0f;   // halo col always interior when valid

    // sliding vertical state: v(new) = p + new; p' = r + new; r' = new
    float pX[4] = {0,0,0,0}, rX[4] = {0,0,0,0};
    float pY[4] = {0,0,0,0}, rY[4] = {0,0,0,0};
    float pXX[4] = {0,0,0,0}, rXX[4] = {0,0,0,0};
    float pXY[4] = {0,0,0,0}, rXY[4] = {0,0,0,0};
    float pHX[2] = {0,0}, rHX[2] = {0,0};
    float pHY[2] = {0,0}, rHY[2] = {0,0};
    float pHXX[2] = {0,0}, rHXX[2] = {0,0};
    float pHXY[2] = {0,0}, rHXY[2] = {0,0};
    float pA[4] = {0,0,0,0}, rA[4] = {0,0,0,0};
    float pB[4] = {0,0,0,0}, rB[4] = {0,0,0,0};
    float pAH = 0, rAH = 0, pBH = 0, rBH = 0;

    int off = (R0 - 2) * W + colA;

    // prime the 2-deep pipeline: row R0-2 -> xv (consumed s=0),
    //                            row R0-1 -> xv1 (consumed s=1)
    float4 xv  = {0,0,0,0}, yv  = {0,0,0,0};
    float2 xh  = {0,0},     yh  = {0,0};
    float4 xv1 = {0,0,0,0}, yv1 = {0,0,0,0};
    float2 xh1 = {0,0},     yh1 = {0,0};
    if (R0 - 2 >= 0) {
        xv = *(const float4*)(xp + off);
        yv = *(const float4*)(yp + off);
        if (haloIn) {
            xh = *(const float2*)(xp + off + hoff);
            yh = *(const float2*)(yp + off + hoff);
        }
    }
    if (R0 - 1 >= 0) {
        xv1 = *(const float4*)(xp + off + W);
        yv1 = *(const float4*)(yp + off + W);
        if (haloIn) {
            xh1 = *(const float2*)(xp + off + W + hoff);
            yh1 = *(const float2*)(yp + off + W + hoff);
        }
    }

#pragma unroll 2
    for (int s = 0; s < STRIP + 4; ++s) {
        const int lr = R0 - 2 + s;   // row held in xv/yv (consumed this step)
        const int t = lr - 1;        // A,b row produced this step
        const int r = lr - 2;        // output row produced this step

        // ---- issue loads for row lr+2 == R0+s (depth-2 prefetch)
        float4 xv2 = {0,0,0,0}, yv2 = {0,0,0,0};
        float2 xh2 = {0,0}, yh2 = {0,0};
        if (s < STRIP + 2 && (unsigned)(R0 + s) < (unsigned)H) {
            const int off2 = off + 2 * W;
            xv2 = *(const float4*)(xp + off2);
            yv2 = *(const float4*)(yp + off2);
            if (haloIn) {
                xh2 = *(const float2*)(xp + off2 + hoff);
                yh2 = *(const float2*)(yp + off2 + hoff);
            }
        }
        // pin the load-issue point: nothing may move across (keeps the
        // prefetch two iterations ahead of its consume-wait)
        __builtin_amdgcn_sched_barrier(0);

        // ---- products + vertical window update (own 4 cols)
        const float x_[4] = {xv.x, xv.y, xv.z, xv.w};
        const float y_[4] = {yv.x, yv.y, yv.z, yv.w};
        float vX[4], vY[4], vXX[4], vXY[4];
#pragma unroll
        for (int c = 0; c < 4; ++c) {
            const float xx = x_[c] * x_[c];
            const float xy = x_[c] * y_[c];
            vX[c]  = pX[c]  + x_[c]; pX[c]  = rX[c]  + x_[c]; rX[c]  = x_[c];
            vY[c]  = pY[c]  + y_[c]; pY[c]  = rY[c]  + y_[c]; rY[c]  = y_[c];
            vXX[c] = pXX[c] + xx;    pXX[c] = rXX[c] + xx;    rXX[c] = xx;
            vXY[c] = pXY[c] + xy;    pXY[c] = rXY[c] + xy;    rXY[c] = xy;
        }
        // halo cols (meaningful only on edge lanes; zeros elsewhere)
        const float xh_[2] = {xh.x, xh.y};
        const float yh_[2] = {yh.x, yh.y};
        float vHX[2], vHY[2], vHXX[2], vHXY[2];
#pragma unroll
        for (int c = 0; c < 2; ++c) {
            const float xx = xh_[c] * xh_[c];
            const float xy = xh_[c] * yh_[c];
            vHX[c]  = pHX[c]  + xh_[c]; pHX[c]  = rHX[c]  + xh_[c]; rHX[c]  = xh_[c];
            vHY[c]  = pHY[c]  + yh_[c]; pHY[c]  = rHY[c]  + yh_[c]; rHY[c]  = yh_[c];
            vHXX[c] = pHXX[c] + xx;     pHXX[c] = rHXX[c] + xx;     rHXX[c] = xx;
            vHXY[c] = pHXY[c] + xy;     pHXY[c] = rHXY[c] + xy;     rHXY[c] = xy;
        }

        // ---- single cross-lane stage on vertical sums (DPP wave shifts)
        float lX  = dpp_up1(vX[3]),  rXs  = dpp_dn1(vX[0]);
        float lY  = dpp_up1(vY[3]),  rYs  = dpp_dn1(vY[0]);
        float lXX = dpp_up1(vXX[3]), rXXs = dpp_dn1(vXX[0]);
        float lXY = dpp_up1(vXY[3]), rXYs = dpp_dn1(vXY[0]);
        lX  = isL ? vHX[1]  : lX;   rXs  = isR ? vHX[0]  : rXs;
        lY  = isL ? vHY[1]  : lY;   rYs  = isR ? vHY[0]  : rYs;
        lXX = isL ? vHXX[1] : lXX;  rXXs = isR ? vHXX[0] : rXXs;
        lXY = isL ? vHXY[1] : lXY;  rXYs = isR ? vHXY[0] : rXYs;

        // ---- horizontal 3-sums (pair-sum trick)
        float hX[4], hY[4], hXX[4], hXY[4];
        {
            const float s01 = vX[0] + vX[1], s12 = vX[1] + vX[2], s23 = vX[2] + vX[3];
            hX[0] = lX + s01; hX[1] = s01 + vX[2]; hX[2] = s12 + vX[3]; hX[3] = s23 + rXs;
        }
        {
            const float s01 = vY[0] + vY[1], s12 = vY[1] + vY[2], s23 = vY[2] + vY[3];
            hY[0] = lY + s01; hY[1] = s01 + vY[2]; hY[2] = s12 + vY[3]; hY[3] = s23 + rYs;
        }
        {
            const float s01 = vXX[0] + vXX[1], s12 = vXX[1] + vXX[2], s23 = vXX[2] + vXX[3];
            hXX[0] = lXX + s01; hXX[1] = s01 + vXX[2]; hXX[2] = s12 + vXX[3]; hXX[3] = s23 + rXXs;
        }
        {
            const float s01 = vXY[0] + vXY[1], s12 = vXY[1] + vXY[2], s23 = vXY[2] + vXY[3];
            hXY[0] = lXY + s01; hXY[1] = s01 + vXY[2]; hXY[2] = s12 + vXY[3]; hXY[3] = s23 + rXYs;
        }

        // ---- stage 1: A,b for row t (rowfA=0 outside image zeroes everything)
        const float rowfA = ((unsigned)t >= (unsigned)H) ? 0.0f
                          : ((t == 0 || t == H - 1) ? 0.5f : third);
        float A_[4], B_[4];
#pragma unroll
        for (int c = 0; c < 4; ++c) {
            const float ic  = rowfA * invc[c];
            const float mx  = hX[c]  * ic;
            const float my  = hY[c]  * ic;
            const float mxx = hXX[c] * ic;
            const float mxy = hXY[c] * ic;
            const float var = fmaf(-mx, mx, mxx);
            const float cov = fmaf(-mx, my, mxy);
            A_[c] = cov * __builtin_amdgcn_rcpf(var + 0.01f);
            B_[c] = fmaf(-A_[c], mx, my);
        }
        // halo-column A,b (one per edge lane; garbage-but-finite elsewhere)
        float AH, BH;
        {
            const float iH  = rowfA * invcH;
            const float hx  = vHX[0]  + vHX[1]  + (isL ? vX[0]  : vX[3]);
            const float hy  = vHY[0]  + vHY[1]  + (isL ? vY[0]  : vY[3]);
            const float hxx = vHXX[0] + vHXX[1] + (isL ? vXX[0] : vXX[3]);
            const float hxy = vHXY[0] + vHXY[1] + (isL ? vXY[0] : vXY[3]);
            const float mx  = hx * iH, my = hy * iH, mxx = hxx * iH, mxy = hxy * iH;
            const float var = fmaf(-mx, mx, mxx);
            const float cov = fmaf(-mx, my, mxy);
            AH = cov * __builtin_amdgcn_rcpf(var + 0.01f);
            BH = fmaf(-AH, mx, my);
        }

        // ---- A,b vertical windows
        float vA[4], vB[4];
#pragma unroll
        for (int c = 0; c < 4; ++c) {
            vA[c] = pA[c] + A_[c]; pA[c] = rA[c] + A_[c]; rA[c] = A_[c];
            vB[c] = pB[c] + B_[c]; pB[c] = rB[c] + B_[c]; rB[c] = B_[c];
        }
        const float vAH = pAH + AH;  pAH = rAH + AH;  rAH = AH;
        const float vBH = pBH + BH;  pBH = rBH + BH;  rBH = BH;

        // ---- cross-lane stage on A,b vertical sums (DPP wave shifts)
        float lA = dpp_up1(vA[3]), rAs = dpp_dn1(vA[0]);
        float lB = dpp_up1(vB[3]), rBs = dpp_dn1(vB[0]);
        lA = isL ? vAH : lA;  rAs = isR ? vAH : rAs;
        lB = isL ? vBH : lB;  rBs = isR ? vBH : rBs;

        // ---- output row r
        if (s >= 4) {
            float hA[4], hB[4];
            {
                const float s01 = vA[0] + vA[1], s12 = vA[1] + vA[2], s23 = vA[2] + vA[3];
                hA[0] = lA + s01; hA[1] = s01 + vA[2]; hA[2] = s12 + vA[3]; hA[3] = s23 + rAs;
            }
            {
                const float s01 = vB[0] + vB[1], s12 = vB[1] + vB[2], s23 = vB[2] + vB[3];
                hB[0] = lB + s01; hB[1] = s01 + vB[2]; hB[2] = s12 + vB[3]; hB[3] = s23 + rBs;
            }
            const float rowfO = (r == 0 || r == H - 1) ? 0.5f : third;
            float4 o;
            float o_[4];
#pragma unroll
            for (int c = 0; c < 4; ++c) {
                const float oc = rowfO * invc[c];
                const float xc = vX[c] - pX[c];     // = x at row r (post-update identity)
                o_[c] = fmaf(hA[c] * oc, xc, hB[c] * oc);
            }
            o.x = o_[0]; o.y = o_[1]; o.z = o_[2]; o.w = o_[3];
            *(float4*)(op + (off - 2 * W)) = o;
        }

        // rotate the 2-deep pipeline (renamed by unroll-2, mostly no movs)
        xv = xv1;  yv = yv1;  xh = xh1;  yh = yh1;
        xv1 = xv2; yv1 = yv2; xh1 = xh2; yh1 = yh2;
        off += W;
    }
}

extern "C" void kernel_launch(void* const* d_in, const int* in_sizes, int n_in,
                              void* d_out, int out_size, void* d_ws, size_t ws_size,
                              hipStream_t stream) {
    const float* x = (const float*)d_in[0];
    const float* y = (const float*)d_in[1];
    float* out = (float*)d_out;
    const int planes = in_sizes[0] / (H * W);                  // N*C = 24
    dim3 grid(W / WVC, H / (STRIP * WAVES), planes);           // 4 x 16 x 24 = 1536
    gf_kernel<<<grid, dim3(256), 0, stream>>>(x, y, out);
}

// Round 3
// 254.068 us; speedup vs baseline: 3.3066x; 3.3066x over previous
//
#include <hip/hip_runtime.h>

// Guided filter r=1, eps=0.01, (8,3,1024,1024) fp32.
// Register-streaming v2: vertical-sums-first, 4 cols/lane (float4), 2-register
// sliding vertical windows (p = prev2+prev1, r = prev1; v = p + new), single
// dependent DPP stage per box pass. Wave strip: 256 cols x 16 rows.
// Edge lanes maintain a 2-col halo pipeline. box()/Nrm == sum/count; count
// applied as exact 0.5 / (1/3) row x col factors.
//
// R1: __shfl -> DPP wave shifts (neutral; cross-lane latency was not the wall).
// R2 FAILED: depth-2 prefetch + sched_barrier(0) + launch_bounds(256,5) ->
//     VGPR capped at 48, per-lane window state spilled to scratch
//     (WRITE_SIZE 98 MB -> 1.2 GB), 700 us. The convoy theory was never
//     tested; the experiment died of register pressure.
// R3: same depth-2 prefetch, WITHOUT the poison: launch_bounds back to
//     (256,3) (no allocator squeeze), no sched_barrier. Unroll-2 renaming
//     carries the extra stage; expected ~84 VGPR, 6 blocks/CU retained.
//     Watch: WRITE_SIZE must stay ~98 MB (else spills are back).

#define H 1024
#define W 1024
#define STRIP 16      // output rows per wave
#define WAVES 4       // waves per block (stacked vertically)
#define WVC 256       // columns per wave (4 per lane)

// lane i receives lane i-1's value (== __shfl_up(v,1,64)); lane 0 -> 0
__device__ __forceinline__ float dpp_up1(float v) {
    return __int_as_float(__builtin_amdgcn_update_dpp(
        0, __float_as_int(v), 0x138 /*wave_shr:1*/, 0xf, 0xf, true));
}
// lane i receives lane i+1's value (== __shfl_down(v,1,64)); lane 63 -> 0
__device__ __forceinline__ float dpp_dn1(float v) {
    return __int_as_float(__builtin_amdgcn_update_dpp(
        0, __float_as_int(v), 0x130 /*wave_shl:1*/, 0xf, 0xf, true));
}

__global__ __launch_bounds__(256, 3) void gf_kernel(const float* __restrict__ xg,
                                                    const float* __restrict__ yg,
                                                    float* __restrict__ og)
{
    const int lane = threadIdx.x & 63;
    const int wv = threadIdx.x >> 6;
    const int c0 = blockIdx.x * WVC;
    const int R0 = (blockIdx.y * WAVES + wv) * STRIP;
    const size_t base = (size_t)blockIdx.z * (size_t)(H * W);
    const float* __restrict__ xp = xg + base;
    const float* __restrict__ yp = yg + base;
    float* __restrict__ op = og + base;

    const int colA = c0 + 4 * lane;          // first of this lane's 4 columns
    const bool isL = (lane == 0);
    const bool isR = (lane == 63);
    // lane0 halo cols: c0-2 (h0), c0-1 (h1).  lane63: c0+256 (h0), c0+257 (h1).
    const bool haloIn = isL ? (c0 > 0) : (isR ? (c0 + WVC < W) : false);
    const int hoff = (isL ? (c0 - 2) : (c0 + WVC)) - colA;

    const float third = 1.0f / 3.0f;
    float invc[4];
    invc[0] = (colA == 0) ? 0.5f : third;        // col%4==0 -> only col 0 possible edge
    invc[1] = third;
    invc[2] = third;
    invc[3] = (colA + 3 == W - 1) ? 0.5f : third;
    const float invcH = haloIn ? third : 0.0f;   // halo col always interior when valid

    // sliding vertical state: v(new) = p + new; p' = r + new; r' = new
    float pX[4] = {0,0,0,0}, rX[4] = {0,0,0,0};
    float pY[4] = {0,0,0,0}, rY[4] = {0,0,0,0};
    float pXX[4] = {0,0,0,0}, rXX[4] = {0,0,0,0};
    float pXY[4] = {0,0,0,0}, rXY[4] = {0,0,0,0};
    float pHX[2] = {0,0}, rHX[2] = {0,0};
    float pHY[2] = {0,0}, rHY[2] = {0,0};
    float pHXX[2] = {0,0}, rHXX[2] = {0,0};
    float pHXY[2] = {0,0}, rHXY[2] = {0,0};
    float pA[4] = {0,0,0,0}, rA[4] = {0,0,0,0};
    float pB[4] = {0,0,0,0}, rB[4] = {0,0,0,0};
    float pAH = 0, rAH = 0, pBH = 0, rBH = 0;

    int off = (R0 - 2) * W + colA;

    // prime the 2-deep pipeline: row R0-2 -> xv (consumed s=0),
    //                            row R0-1 -> xv1 (consumed s=1)
    float4 xv  = {0,0,0,0}, yv  = {0,0,0,0};
    float2 xh  = {0,0},     yh  = {0,0};
    float4 xv1 = {0,0,0,0}, yv1 = {0,0,0,0};
    float2 xh1 = {0,0},     yh1 = {0,0};
    if (R0 - 2 >= 0) {
        xv = *(const float4*)(xp + off);
        yv = *(const float4*)(yp + off);
        if (haloIn) {
            xh = *(const float2*)(xp + off + hoff);
            yh = *(const float2*)(yp + off + hoff);
        }
    }
    if (R0 - 1 >= 0) {
        xv1 = *(const float4*)(xp + off + W);
        yv1 = *(const float4*)(yp + off + W);
        if (haloIn) {
            xh1 = *(const float2*)(xp + off + W + hoff);
            yh1 = *(const float2*)(yp + off + W + hoff);
        }
    }

#pragma unroll 2
    for (int s = 0; s < STRIP + 4; ++s) {
        const int lr = R0 - 2 + s;   // row held in xv/yv (consumed this step)
        const int t = lr - 1;        // A,b row produced this step
        const int r = lr - 2;        // output row produced this step

        // ---- issue loads for row lr+2 == R0+s (depth-2 prefetch; consumed
        //      two iterations from now, ~900+ cycles of independent work)
        float4 xv2 = {0,0,0,0}, yv2 = {0,0,0,0};
        float2 xh2 = {0,0}, yh2 = {0,0};
        if (s < STRIP + 2 && (unsigned)(R0 + s) < (unsigned)H) {
            const int off2 = off + 2 * W;
            xv2 = *(const float4*)(xp + off2);
            yv2 = *(const float4*)(yp + off2);
            if (haloIn) {
                xh2 = *(const float2*)(xp + off2 + hoff);
                yh2 = *(const float2*)(yp + off2 + hoff);
            }
        }

        // ---- products + vertical window update (own 4 cols)
        const float x_[4] = {xv.x, xv.y, xv.z, xv.w};
        const float y_[4] = {yv.x, yv.y, yv.z, yv.w};
        float vX[4], vY[4], vXX[4], vXY[4];
#pragma unroll
        for (int c = 0; c < 4; ++c) {
            const float xx = x_[c] * x_[c];
            const float xy = x_[c] * y_[c];
            vX[c]  = pX[c]  + x_[c]; pX[c]  = rX[c]  + x_[c]; rX[c]  = x_[c];
            vY[c]  = pY[c]  + y_[c]; pY[c]  = rY[c]  + y_[c]; rY[c]  = y_[c];
            vXX[c] = pXX[c] + xx;    pXX[c] = rXX[c] + xx;    rXX[c] = xx;
            vXY[c] = pXY[c] + xy;    pXY[c] = rXY[c] + xy;    rXY[c] = xy;
        }
        // halo cols (meaningful only on edge lanes; zeros elsewhere)
        const float xh_[2] = {xh.x, xh.y};
        const float yh_[2] = {yh.x, yh.y};
        float vHX[2], vHY[2], vHXX[2], vHXY[2];
#pragma unroll
        for (int c = 0; c < 2; ++c) {
            const float xx = xh_[c] * xh_[c];
            const float xy = xh_[c] * yh_[c];
            vHX[c]  = pHX[c]  + xh_[c]; pHX[c]  = rHX[c]  + xh_[c]; rHX[c]  = xh_[c];
            vHY[c]  = pHY[c]  + yh_[c]; pHY[c]  = rHY[c]  + yh_[c]; rHY[c]  = yh_[c];
            vHXX[c] = pHXX[c] + xx;     pHXX[c] = rHXX[c] + xx;     rHXX[c] = xx;
            vHXY[c] = pHXY[c] + xy;     pHXY[c] = rHXY[c] + xy;     rHXY[c] = xy;
        }

        // ---- single cross-lane stage on vertical sums (DPP wave shifts)
        float lX  = dpp_up1(vX[3]),  rXs  = dpp_dn1(vX[0]);
        float lY  = dpp_up1(vY[3]),  rYs  = dpp_dn1(vY[0]);
        float lXX = dpp_up1(vXX[3]), rXXs = dpp_dn1(vXX[0]);
        float lXY = dpp_up1(vXY[3]), rXYs = dpp_dn1(vXY[0]);
        lX  = isL ? vHX[1]  : lX;   rXs  = isR ? vHX[0]  : rXs;
        lY  = isL ? vHY[1]  : lY;   rYs  = isR ? vHY[0]  : rYs;
        lXX = isL ? vHXX[1] : lXX;  rXXs = isR ? vHXX[0] : rXXs;
        lXY = isL ? vHXY[1] : lXY;  rXYs = isR ? vHXY[0] : rXYs;

        // ---- horizontal 3-sums (pair-sum trick)
        float hX[4], hY[4], hXX[4], hXY[4];
        {
            const float s01 = vX[0] + vX[1], s12 = vX[1] + vX[2], s23 = vX[2] + vX[3];
            hX[0] = lX + s01; hX[1] = s01 + vX[2]; hX[2] = s12 + vX[3]; hX[3] = s23 + rXs;
        }
        {
            const float s01 = vY[0] + vY[1], s12 = vY[1] + vY[2], s23 = vY[2] + vY[3];
            hY[0] = lY + s01; hY[1] = s01 + vY[2]; hY[2] = s12 + vY[3]; hY[3] = s23 + rYs;
        }
        {
            const float s01 = vXX[0] + vXX[1], s12 = vXX[1] + vXX[2], s23 = vXX[2] + vXX[3];
            hXX[0] = lXX + s01; hXX[1] = s01 + vXX[2]; hXX[2] = s12 + vXX[3]; hXX[3] = s23 + rXXs;
        }
        {
            const float s01 = vXY[0] + vXY[1], s12 = vXY[1] + vXY[2], s23 = vXY[2] + vXY[3];
            hXY[0] = lXY + s01; hXY[1] = s01 + vXY[2]; hXY[2] = s12 + vXY[3]; hXY[3] = s23 + rXYs;
        }

        // ---- stage 1: A,b for row t (rowfA=0 outside image zeroes everything)
        const float rowfA = ((unsigned)t >= (unsigned)H) ? 0.0f
                          : ((t == 0 || t == H - 1) ? 0.5f : third);
        float A_[4], B_[4];
#pragma unroll
        for (int c = 0; c < 4; ++c) {
            const float ic  = rowfA * invc[c];
            const float mx  = hX[c]  * ic;
            const float my  = hY[c]  * ic;
            const float mxx = hXX[c] * ic;
            const float mxy = hXY[c] * ic;
            const float var = fmaf(-mx, mx, mxx);
            const float cov = fmaf(-mx, my, mxy);
            A_[c] = cov * __builtin_amdgcn_rcpf(var + 0.01f);
            B_[c] = fmaf(-A_[c], mx, my);
        }
        // halo-column A,b (one per edge lane; garbage-but-finite elsewhere)
        float AH, BH;
        {
            const float iH  = rowfA * invcH;
            const float hx  = vHX[0]  + vHX[1]  + (isL ? vX[0]  : vX[3]);
            const float hy  = vHY[0]  + vHY[1]  + (isL ? vY[0]  : vY[3]);
            const float hxx = vHXX[0] + vHXX[1] + (isL ? vXX[0] : vXX[3]);
            const float hxy = vHXY[0] + vHXY[1] + (isL ? vXY[0] : vXY[3]);
            const float mx  = hx * iH, my = hy * iH, mxx = hxx * iH, mxy = hxy * iH;
            const float var = fmaf(-mx, mx, mxx);
            const float cov = fmaf(-mx, my, mxy);
            AH = cov * __builtin_amdgcn_rcpf(var + 0.01f);
            BH = fmaf(-AH, mx, my);
        }

        // ---- A,b vertical windows
        float vA[4], vB[4];
#pragma unroll
        for (int c = 0; c < 4; ++c) {
            vA[c] = pA[c] + A_[c]; pA[c] = rA[c] + A_[c]; rA[c] = A_[c];
            vB[c] = pB[c] + B_[c]; pB[c] = rB[c] + B_[c]; rB[c] = B_[c];
        }
        const float vAH = pAH + AH;  pAH = rAH + AH;  rAH = AH;
        const float vBH = pBH + BH;  pBH = rBH + BH;  rBH = BH;

        // ---- cross-lane stage on A,b vertical sums (DPP wave shifts)
        float lA = dpp_up1(vA[3]), rAs = dpp_dn1(vA[0]);
        float lB = dpp_up1(vB[3]), rBs = dpp_dn1(vB[0]);
        lA = isL ? vAH : lA;  rAs = isR ? vAH : rAs;
        lB = isL ? vBH : lB;  rBs = isR ? vBH : rBs;

        // ---- output row r
        if (s >= 4) {
            float hA[4], hB[4];
            {
                const float s01 = vA[0] + vA[1], s12 = vA[1] + vA[2], s23 = vA[2] + vA[3];
                hA[0] = lA + s01; hA[1] = s01 + vA[2]; hA[2] = s12 + vA[3]; hA[3] = s23 + rAs;
            }
            {
                const float s01 = vB[0] + vB[1], s12 = vB[1] + vB[2], s23 = vB[2] + vB[3];
                hB[0] = lB + s01; hB[1] = s01 + vB[2]; hB[2] = s12 + vB[3]; hB[3] = s23 + rBs;
            }
            const float rowfO = (r == 0 || r == H - 1) ? 0.5f : third;
            float4 o;
            float o_[4];
#pragma unroll
            for (int c = 0; c < 4; ++c) {
                const float oc = rowfO * invc[c];
                const float xc = vX[c] - pX[c];     // = x at row r (post-update identity)
                o_[c] = fmaf(hA[c] * oc, xc, hB[c] * oc);
            }
            o.x = o_[0]; o.y = o_[1]; o.z = o_[2]; o.w = o_[3];
            *(float4*)(op + (off - 2 * W)) = o;
        }

        // rotate the 2-deep pipeline (renamed by unroll-2, mostly no movs)
        xv = xv1;  yv = yv1;  xh = xh1;  yh = yh1;
        xv1 = xv2; yv1 = yv2; xh1 = xh2; yh1 = yh2;
        off += W;
    }
}

extern "C" void kernel_launch(void* const* d_in, const int* in_sizes, int n_in,
                              void* d_out, int out_size, void* d_ws, size_t ws_size,
                              hipStream_t stream) {
    const float* x = (const float*)d_in[0];
    const float* y = (const float*)d_in[1];
    float* out = (float*)d_out;
    const int planes = in_sizes[0] / (H * W);                  // N*C = 24
    dim3 grid(W / WVC, H / (STRIP * WAVES), planes);           // 4 x 16 x 24 = 1536
    gf_kernel<<<grid, dim3(256), 0, stream>>>(x, y, out);
}